// Round 6
// baseline (524.896 us; speedup 1.0000x reference)
//
#include <hip/hip_runtime.h>

#define NN 4096
#define EPS 1e-5f

// ---------------- workspace layout (float offsets) ----------------
#define Q_OFF   0u              // [B][N][8]      131072
#define K_OFF   131072u         // [B][8][N]      131072
#define V_OFF   262144u         // [B][64][N]    1048576
#define O_OFF   1310720u        // PAM out [B][64][N]
#define Y_OFF   2359296u        // y [B][64][N]
#define OC_OFF  3407872u        // CAM raw out
#define AT_OFF  4456448u        // attn_c [B][64][64] 16384
#define S2_OFF  4472832u        // CAM sums: sum[64], sumsq[64]
#define PS_OFF  4472960u        // PAM sums: sum[64], sumsq[64]
#define GP_OFF  4473088u        // gram partials [B*64][64][64] (1048576)

// ---------------- projections: q,k,v (x staged via LDS) ----------------
__global__ __launch_bounds__(256) void proj_kernel(
    const float* __restrict__ x, const float* __restrict__ Wq, const float* __restrict__ bq,
    const float* __restrict__ Wk, const float* __restrict__ bk,
    const float* __restrict__ Wv, const float* __restrict__ bv,
    float* __restrict__ q, float* __restrict__ k, float* __restrict__ v) {
  __shared__ float sWq[8*64], sWk[8*64], sWv[64*64], sbq[8], sbk[8], sbv[64];
  __shared__ float xt[64*68];
  int t = threadIdx.x;
  int b = blockIdx.x >> 6;
  int sp = blockIdx.x & 63;
  int n0 = sp << 6;
  for (int i = t; i < 512; i += 256) { sWq[i] = Wq[i]; sWk[i] = Wk[i]; }
  for (int i = t; i < 4096; i += 256) sWv[i] = Wv[i];
  if (t < 64) sbv[t] = bv[t];
  if (t < 8) { sbq[t] = bq[t]; sbk[t] = bk[t]; }
  // stage x tile [c][n] coalesced (direct x reads would be stride-16KB per c)
  for (int i = t; i < 1024; i += 256) {
    int c = i >> 4, nf = (i & 15) << 2;
    *(float4*)&xt[c*68 + nf] =
        *(const float4*)&x[(size_t)(((b<<6)|c)<<12) + n0 + nf];
  }
  __syncthreads();
  int nl = t & 63;
  int n = n0 | nl;
  int cg_ = t >> 6;
  float xv[64];
  #pragma unroll
  for (int c = 0; c < 64; ++c) xv[c] = xt[c*68 + nl];
  for (int c = cg_*16; c < cg_*16+16; ++c) {
    float acc = sbv[c];
    #pragma unroll
    for (int c2 = 0; c2 < 64; ++c2) acc += sWv[c*64 + c2] * xv[c2];
    v[(((b<<6)|c)<<12) | n] = acc;
  }
  if (cg_ == 0) {
    #pragma unroll
    for (int d = 0; d < 8; ++d) {
      float acc = sbq[d];
      #pragma unroll
      for (int c = 0; c < 64; ++c) acc += sWq[d*64+c] * xv[c];
      q[(((b<<12)|n)<<3) | d] = acc;
    }
  } else if (cg_ == 1) {
    #pragma unroll
    for (int d = 0; d < 8; ++d) {
      float acc = sbk[d];
      #pragma unroll
      for (int c = 0; c < 64; ++c) acc += sWk[d*64+c] * xv[c];
      k[(((b<<3)|d)<<12) | n] = acc;
    }
  }
}

// ---------------- flash attention (PAM): full sweep, 4 thread-quarters ----
// 256 blocks x 1024 threads (16 waves/CU, same occupancy as r2's 4x4-wave
// split but with NO 16MB partials / merge kernel).  Quarter h = t>>8 runs
// the verbatim r2 per-thread code (4x4 PV tiles, register denominators) on
// chunks n0 = h*64, h*64+256, ... with its own kst/vst/pst.  End: in-LDS
// quarter merge, normalize, transpose, store o once + fused BN1 stats.
__global__ __launch_bounds__(1024, 1) void attn_kernel(
    const float* __restrict__ q, const float* __restrict__ k,
    const float* __restrict__ v, float* __restrict__ o,
    float* __restrict__ psums) {
  __shared__ float kst[4][64*12];   // [ni][d], pad 12 (3 KB each)
  __shared__ float vst[4][64*68];   // [ni][c], pad 68 (17 KB each)
  __shared__ float pst[4][64*68];   // [ni][m], pad 68

  const int b  = blockIdx.x >> 6;
  const int m0 = (blockIdx.x & 63) << 6;
  const int t  = threadIdx.x;
  const int h  = t >> 8;        // quarter 0..3 (wave-uniform)
  const int u  = t & 255;
  const int rq = u & 15;        // score: rows 4rq..4rq+3 ; PV: cols 4rq..
  const int sg = u >> 4;        // score: ni 4sg..4sg+3   ; PV: rows 4sg..

  // q for this thread's 4 score rows (same rows in every quarter)
  float4 qa[4][2];
  #pragma unroll
  for (int r = 0; r < 4; ++r) {
    const float4* qp = (const float4*)&q[(size_t)(((b<<12) | (m0 + (rq<<2) + r)) << 3)];
    qa[r][0] = qp[0]; qa[r][1] = qp[1];
  }

  float lsum[4] = {0.f, 0.f, 0.f, 0.f};
  float av[4][4] = {{0.f}};

  for (int n0 = h << 6; n0 < NN; n0 += 256) {     // 16 iters per quarter
    __syncthreads();             // prev PV reads of vst/pst done
    // stage K chunk transposed: kst[h][ni][d]
    #pragma unroll
    for (int i = u; i < 512; i += 256) {
      int ni = i & 63, d = i >> 6;
      kst[h][ni*12 + d] = k[(((b<<3)|d)<<12) + n0 + ni];
    }
    // stage V chunk transposed: vst[h][ni][c]
    #pragma unroll
    for (int i = u; i < 4096; i += 256) {
      int ni = i & 63, c = i >> 6;
      vst[h][ni*68 + c] = v[(((b<<6)|c)<<12) + n0 + ni];
    }
    __syncthreads();
    // scores: thread (rq, sg) -> rows 4rq.., ni 4sg..4sg+3
    #pragma unroll
    for (int j = 0; j < 4; ++j) {
      const int ni = (sg << 2) | j;
      const float4 ka = *(const float4*)&kst[h][ni*12];
      const float4 kb = *(const float4*)&kst[h][ni*12 + 4];
      float pj[4];
      #pragma unroll
      for (int r = 0; r < 4; ++r) {
        float s = qa[r][0].x*ka.x + qa[r][0].y*ka.y + qa[r][0].z*ka.z + qa[r][0].w*ka.w
                + qa[r][1].x*kb.x + qa[r][1].y*kb.y + qa[r][1].z*kb.z + qa[r][1].w*kb.w;
        float e = __expf(s);     // no-max softmax (validated r1-r4)
        pj[r] = e;
        lsum[r] += e;
      }
      *(float4*)&pst[h][ni*68 + (rq<<2)] = make_float4(pj[0], pj[1], pj[2], pj[3]);
    }
    __syncthreads();
    // PV: thread (sg=m-group, rq=c-group), 4x4 tile
    #pragma unroll 4
    for (int ni = 0; ni < 64; ++ni) {
      const float4 p4 = *(const float4*)&pst[h][ni*68 + (sg<<2)];
      const float4 v4 = *(const float4*)&vst[h][ni*68 + (rq<<2)];
      av[0][0] += p4.x*v4.x; av[0][1] += p4.x*v4.y; av[0][2] += p4.x*v4.z; av[0][3] += p4.x*v4.w;
      av[1][0] += p4.y*v4.x; av[1][1] += p4.y*v4.y; av[1][2] += p4.y*v4.z; av[1][3] += p4.y*v4.w;
      av[2][0] += p4.z*v4.x; av[2][1] += p4.z*v4.y; av[2][2] += p4.z*v4.z; av[2][3] += p4.z*v4.w;
      av[3][0] += p4.w*v4.x; av[3][1] += p4.w*v4.y; av[3][2] += p4.w*v4.z; av[3][3] += p4.w*v4.w;
    }
  }
  // ---- quarter merge ----
  __syncthreads();
  if (h > 0) {                   // quarters 1..3 publish av + lsum
    float* pav = pst[h];
    #pragma unroll
    for (int r = 0; r < 4; ++r)
      #pragma unroll
      for (int cc = 0; cc < 4; ++cc)
        pav[(u<<4) + (r<<2) + cc] = av[r][cc];
    float* plv = vst[h];
    #pragma unroll
    for (int r = 0; r < 4; ++r) plv[(u<<2) + r] = lsum[r];
  }
  __syncthreads();
  if (h == 0) {                  // quarter 0 accumulates
    #pragma unroll
    for (int qq = 1; qq < 4; ++qq) {
      #pragma unroll
      for (int r = 0; r < 4; ++r) {
        #pragma unroll
        for (int cc = 0; cc < 4; ++cc)
          av[r][cc] += pst[qq][(u<<4) + (r<<2) + cc];
        lsum[r] += vst[qq][(u<<2) + r];
      }
    }
    // row-sum partials into pst[0] scratch: pst0[sg][row]
    *(float4*)&pst[0][sg*68 + (rq<<2)] = make_float4(lsum[0], lsum[1], lsum[2], lsum[3]);
  }
  __syncthreads();
  if (t < 64) {
    float l = 0.f;
    #pragma unroll
    for (int s = 0; s < 16; ++s) l += pst[0][s*68 + t];
    kst[0][t] = 1.f / l;         // linv
  }
  __syncthreads();
  if (h == 0) {                  // normalize + transpose into sm=[c][m] pad 65
    float* sm = vst[0];
    #pragma unroll
    for (int r = 0; r < 4; ++r) {
      const int m = (sg<<2) + r;
      const float inv = kst[0][m];
      #pragma unroll
      for (int cc = 0; cc < 4; ++cc)
        sm[((rq<<2)+cc)*65 + m] = av[r][cc] * inv;
    }
  }
  __syncthreads();
  // all 1024: coalesced o store + fused BN1 stats (wave-uniform c)
  {
    const int mloc = t & 63;
    const int wv = t >> 6;       // 0..15
    const float* sm = vst[0];
    #pragma unroll
    for (int it = 0; it < 4; ++it) {
      const int c = (it<<4) + wv;
      float ov = sm[c*65 + mloc];
      o[(size_t)(((b<<6)|c)<<12) + m0 + mloc] = ov;
      float s1 = ov, s2 = ov*ov;
      #pragma unroll
      for (int off = 32; off; off >>= 1) {
        s1 += __shfl_xor(s1, off, 64);
        s2 += __shfl_xor(s2, off, 64);
      }
      if ((t & 63) == 0) { atomicAdd(&psums[c], s1); atomicAdd(&psums[64+c], s2); }
    }
  }
}

// ---------------- yg: BN1 coefs + y = o*A1+B1+x + gram partials ----------------
// (verbatim round 4 — passed correctness)
__global__ __launch_bounds__(256) void yg_kernel(
    const float* __restrict__ o, const float* __restrict__ x,
    const float* __restrict__ psums,
    const float* __restrict__ gp, const float* __restrict__ w1, const float* __restrict__ bb1,
    float* __restrict__ y, float* __restrict__ gpart) {
  __shared__ float yt[64*68];    // [c][m]
  __shared__ float cf[128];
  const int bi = blockIdx.x;
  const int b = bi >> 6, sp = bi & 63;
  const int t = threadIdx.x;
  const int n0 = sp << 6;
  if (t < 64) {
    float m1 = psums[t] * (1.f/16384.f), m2 = psums[64+t] * (1.f/16384.f);
    float var = m2 - m1*m1;
    float gg = *gp;
    float r = rsqrtf(gg*gg*var + EPS);
    float a = gg * r * w1[t];
    cf[t] = a; cf[64+t] = bb1[t] - m1*a;
  }
  __syncthreads();
  #pragma unroll
  for (int i = 0; i < 16; ++i) {
    int idx = (i<<8) + t;
    int c = idx >> 6, m = idx & 63;    // c wave-uniform, m coalesced
    size_t gi = ((size_t)(((b<<6)|c)<<12)) + n0 + m;
    float yv = o[gi]*cf[c] + cf[64+c] + x[gi];
    yt[c*68 + m] = yv;
    y[gi] = yv;
  }
  __syncthreads();
  {
    int tc = t >> 4, td = t & 15;
    float acc[4][4] = {{0.f}};
    #pragma unroll
    for (int mj = 0; mj < 16; ++mj) {
      float4 ya[4], yb[4];
      #pragma unroll
      for (int r = 0; r < 4; ++r)  ya[r] = *(const float4*)&yt[((tc<<2)+r)*68 + (mj<<2)];
      #pragma unroll
      for (int ss = 0; ss < 4; ++ss) yb[ss] = *(const float4*)&yt[((td<<2)+ss)*68 + (mj<<2)];
      #pragma unroll
      for (int r = 0; r < 4; ++r)
        #pragma unroll
        for (int ss = 0; ss < 4; ++ss)
          acc[r][ss] += ya[r].x*yb[ss].x + ya[r].y*yb[ss].y + ya[r].z*yb[ss].z + ya[r].w*yb[ss].w;
    }
    float* gb = gpart + ((size_t)bi << 12);
    #pragma unroll
    for (int r = 0; r < 4; ++r)
      *(float4*)&gb[(((tc<<2)+r)<<6) | (td<<2)] =
          make_float4(acc[r][0], acc[r][1], acc[r][2], acc[r][3]);
  }
}

// ---------------- csm: reduce gram partials + row softmax -> attnc ----------------
// (verbatim round 4 — passed correctness)
__global__ __launch_bounds__(256) void csm_kernel(
    const float* __restrict__ gpart, float* __restrict__ attnc) {
  __shared__ float red[256];
  const int bi = blockIdx.x;
  const int b = bi >> 6, row = bi & 63;
  const int t = threadIdx.x;
  const int d = t & 63, spg = t >> 6;
  float e = 0.f;
  #pragma unroll
  for (int j = 0; j < 16; ++j) {
    int spp = (spg<<4) + j;
    e += gpart[((size_t)((b<<6)|spp) << 12) + (row<<6) + d];
  }
  red[t] = e;
  __syncthreads();
  if (t < 64) {
    float ee = red[t]+red[64+t]+red[128+t]+red[192+t];
    float mn = ee;
    #pragma unroll
    for (int off = 32; off; off >>= 1) mn = fminf(mn, __shfl_xor(mn, off, 64));
    float p = __expf(mn - ee);           // softmax(max-e) == exp(min-e)/sum
    float s = p;
    #pragma unroll
    for (int off = 32; off; off >>= 1) s += __shfl_xor(s, off, 64);
    attnc[(((b<<6)|row)<<6) | t] = p / s;
  }
}

// ---------------- out_c = attn_c @ y  (+ fused BN2 stats) ----------------
// (verbatim round 2/4 — passed correctness)
__global__ __launch_bounds__(256) void cam_apply_kernel(
    const float* __restrict__ attn, const float* __restrict__ y,
    float* __restrict__ oc, float* __restrict__ sums) {
  __shared__ float satt[64*68];
  int b = blockIdx.x >> 6;
  int n = ((blockIdx.x & 63) << 6) | (threadIdx.x & 63);
  int cg_ = threadIdx.x >> 6;
  for (int i = threadIdx.x; i < 4096; i += 256)
    satt[(i>>6)*68 + (i&63)] = attn[(b<<12) | i];
  __syncthreads();
  float yv[64];
  #pragma unroll
  for (int d = 0; d < 64; ++d) yv[d] = y[(((b<<6)|d)<<12) | n];
  for (int c = cg_*16; c < cg_*16+16; ++c) {
    float acc = 0.f;
    #pragma unroll
    for (int d4 = 0; d4 < 16; ++d4) {
      float4 avv = *(const float4*)&satt[c*68 + (d4<<2)];
      acc += avv.x*yv[d4*4] + avv.y*yv[d4*4+1] + avv.z*yv[d4*4+2] + avv.w*yv[d4*4+3];
    }
    oc[(((b<<6)|c)<<12) | n] = acc;
    float s1 = acc, s2 = acc*acc;
    #pragma unroll
    for (int off = 32; off; off >>= 1) { s1 += __shfl_xor(s1, off, 64); s2 += __shfl_xor(s2, off, 64); }
    if ((threadIdx.x & 63) == 0) { atomicAdd(&sums[c], s1); atomicAdd(&sums[64+c], s2); }
  }
}

// ---------------- fin: BN2 coefs + out = oc*A2 + B2 + y ----------------
// (verbatim round 4 — passed correctness)
__global__ __launch_bounds__(256) void fin_kernel(
    const float* __restrict__ oc, const float* __restrict__ y,
    const float* __restrict__ s2b,
    const float* __restrict__ gc, const float* __restrict__ w2, const float* __restrict__ bb2,
    float* __restrict__ out) {
  __shared__ float cf[128];
  const int bi = blockIdx.x;
  const int b = bi >> 6, sp = bi & 63;
  const int t = threadIdx.x;
  const int n0 = sp << 6;
  if (t < 64) {
    float m1 = s2b[t] * (1.f/16384.f), m2 = s2b[64+t] * (1.f/16384.f);
    float var = m2 - m1*m1;
    float gg = *gc;
    float r = rsqrtf(gg*gg*var + EPS);
    float a = gg * r * w2[t];
    cf[t] = a; cf[64+t] = bb2[t] - m1*a;
  }
  __syncthreads();
  const int n = t & 63, cg_ = t >> 6;
  #pragma unroll
  for (int j = 0; j < 16; ++j) {
    int c = (cg_<<4) + j;               // wave-uniform c, lanes sweep n
    size_t gi = ((size_t)(((b<<6)|c)<<12)) + n0 + n;
    out[gi] = oc[gi]*cf[c] + cf[64+c] + y[gi];
  }
}

extern "C" void kernel_launch(void* const* d_in, const int* in_sizes, int n_in,
                              void* d_out, int out_size, void* d_ws, size_t ws_size,
                              hipStream_t stream) {
  (void)in_sizes; (void)n_in; (void)out_size; (void)ws_size;
  const float* x      = (const float*)d_in[0];
  const float* Wq     = (const float*)d_in[1];
  const float* bq     = (const float*)d_in[2];
  const float* Wk     = (const float*)d_in[3];
  const float* bk     = (const float*)d_in[4];
  const float* Wv     = (const float*)d_in[5];
  const float* bv     = (const float*)d_in[6];
  const float* gp     = (const float*)d_in[7];
  const float* bnp_w  = (const float*)d_in[8];
  const float* bnp_b  = (const float*)d_in[9];
  const float* gc     = (const float*)d_in[10];
  const float* bnc_w  = (const float*)d_in[11];
  const float* bnc_b  = (const float*)d_in[12];

  float* ws = (float*)d_ws;
  float* q     = ws + Q_OFF;
  float* k     = ws + K_OFF;
  float* v     = ws + V_OFF;
  float* o     = ws + O_OFF;
  float* y     = ws + Y_OFF;
  float* oc    = ws + OC_OFF;
  float* atc   = ws + AT_OFF;
  float* s2b   = ws + S2_OFF;
  float* ps    = ws + PS_OFF;
  float* gpart = ws + GP_OFF;

  // zero BN stat accumulators (s2b then ps, contiguous 256 floats)
  hipMemsetAsync(s2b, 0, 256u * sizeof(float), stream);

  proj_kernel<<<256, 256, 0, stream>>>(x, Wq, bq, Wk, bk, Wv, bv, q, k, v);
  attn_kernel<<<256, 1024, 0, stream>>>(q, k, v, o, ps);
  yg_kernel<<<256, 256, 0, stream>>>(o, x, ps, gp, bnp_w, bnp_b, y, gpart);
  csm_kernel<<<256, 256, 0, stream>>>(gpart, atc);
  cam_apply_kernel<<<256, 256, 0, stream>>>(atc, y, oc, s2b);
  fin_kernel<<<256, 256, 0, stream>>>(oc, y, s2b, gc, bnc_w, bnc_b, (float*)d_out);
}